// Round 3
// baseline (7382.244 us; speedup 1.0000x reference)
//
#include <hip/hip_runtime.h>

#define BB 8
#define TT 2048
#define DD 64
#define HH 1024
#define OO 16
#define NGRP 16
#define GBLK 16
#define KCH 16
#define CHUNK 128
#define WASH 192
#define STEPS (CHUNK + WASH)

typedef __attribute__((ext_vector_type(8))) short short8;
typedef __attribute__((ext_vector_type(4))) float f32x4;

// ws layout (f32 units)
#define WS_FLAGS 0                       // [16 grp][64] u32
#define WS_HHI   1024                    // [NGRP][2][KCH][HH] bf16 = 262144 f32 slots
#define WS_HLO   (WS_HHI + 262144)
#define WS_UHI   (WS_HLO + 262144)      // [BB][TT][DD] bf16 = 524288 f32 slots
#define WS_ULO   (WS_UHI + 524288)
#define WS_PART  (WS_ULO + 524288)      // [NGRP][GBLK][TT][OO] f32

__device__ __forceinline__ unsigned short f2bf(float x) {
  union { float f; unsigned u; } v; v.f = x;
  unsigned r = v.u + 0x7FFF + ((v.u >> 16) & 1);   // RNE
  return (unsigned short)(r >> 16);
}
__device__ __forceinline__ float bf2f(unsigned short h) {
  union { unsigned u; float f; } v; v.u = ((unsigned)h) << 16; return v.f;
}
// LDS swizzles: 2 lanes/bank (free) for both the ds_add and the readers
__device__ __forceinline__ int zidx(int row, int ch) {
  return (row * 16 + ch) ^ (((row >> 2) & 1) << 4);
}
__device__ __forceinline__ int hidx(int row, int ch) {
  return (row * 16 + ch) ^ (((row >> 4) & 1) << 4);
}

__global__ __launch_bounds__(256) void ucvt_kernel(const float* __restrict__ u,
    unsigned short* __restrict__ uhi, unsigned short* __restrict__ ulo) {
  int i = blockIdx.x * 256 + threadIdx.x;          // 4 elems each, 1,048,576 total
  float4 v = ((const float4*)u)[i];
  ushort4 h, l;
  float x;
  x = v.x; h.x = f2bf(x); l.x = f2bf(x - bf2f(h.x));
  x = v.y; h.y = f2bf(x); l.y = f2bf(x - bf2f(h.y));
  x = v.z; h.z = f2bf(x); l.z = f2bf(x - bf2f(h.z));
  x = v.w; h.w = f2bf(x); l.w = f2bf(x - bf2f(h.w));
  ((ushort4*)uhi)[i] = h;
  ((ushort4*)ulo)[i] = l;
}

__global__ __launch_bounds__(512, 2) void esn_kernel(
    const float* __restrict__ w, const float* __restrict__ w_in,
    const float* __restrict__ w_bias, const float* __restrict__ w_out,
    float* __restrict__ ws)
{
  __shared__ float z_sh[HH];          // [64 rows][16 chains], zidx-swizzled
  __shared__ float hn_sh[HH];         // hidx-swizzled
  __shared__ float wout_sh[64 * 17];  // padded stride 17

  const int tid = threadIdx.x;
  const int lane = tid & 63;
  const int rg = tid >> 6;            // wave 0..7 (owns k-tiles 4rg..4rg+3)
  const int lm = lane & 15;
  const int l4 = lane >> 4;
  const int bid = blockIdx.x;
  const int grp = bid & 15;           // blocks of a group land on one XCD
  const int blk = bid >> 4;
  const int dir = grp >> 3;
  const int b = grp & 7;
  const int row0 = blk * 64;

  unsigned* flags = (unsigned*)ws + grp * 64;
  unsigned short* hhi = (unsigned short*)(ws + WS_HHI);
  unsigned short* hlo = (unsigned short*)(ws + WS_HLO);
  const unsigned short* uhi = (const unsigned short*)(ws + WS_UHI);
  const unsigned short* ulo = (const unsigned short*)(ws + WS_ULO);
  float* partial = ws + WS_PART;

  // ---- A fragments: W rows [row0+mt*16+lm], k = (rg*4+kt)*32 + l4*8 + i  (bf16 hi/lo)
  short8 Ahi[4][4], Alo[4][4];
#pragma unroll
  for (int mt = 0; mt < 4; ++mt) {
#pragma unroll
    for (int kt = 0; kt < 4; ++kt) {
      const int row = row0 + mt * 16 + lm;
      const int kb = (rg * 4 + kt) * 32 + l4 * 8;
      const float* wp = w + (size_t)row * HH + kb;
      short8 h8, l8;
#pragma unroll
      for (int i2 = 0; i2 < 2; ++i2) {
        float4 v = ((const float4*)wp)[i2];
        float xs[4] = {v.x, v.y, v.z, v.w};
#pragma unroll
        for (int j = 0; j < 4; ++j) {
          unsigned short hb = f2bf(xs[j]);
          h8[i2 * 4 + j] = (short)hb;
          l8[i2 * 4 + j] = (short)f2bf(xs[j] - bf2f(hb));
        }
      }
      Ahi[mt][kt] = h8; Alo[mt][kt] = l8;
    }
  }
  // ---- w_in fragments on waves 0,1 (u-projection K=64 -> 2 k-tiles)
  short8 UAhi[4], UAlo[4];
  if (rg < 2) {
#pragma unroll
    for (int mt = 0; mt < 4; ++mt) {
      const int row = row0 + mt * 16 + lm;
      const int kb = rg * 32 + l4 * 8;
      const float* wp = w_in + (size_t)row * DD + kb;
      short8 h8, l8;
#pragma unroll
      for (int i2 = 0; i2 < 2; ++i2) {
        float4 v = ((const float4*)wp)[i2];
        float xs[4] = {v.x, v.y, v.z, v.w};
#pragma unroll
        for (int j = 0; j < 4; ++j) {
          unsigned short hb = f2bf(xs[j]);
          h8[i2 * 4 + j] = (short)hb;
          l8[i2 * 4 + j] = (short)f2bf(xs[j] - bf2f(hb));
        }
      }
      UAhi[mt] = h8; UAlo[mt] = l8;
    }
  }

  // w_out slice -> LDS (padded)
  for (int idx = tid; idx < 1024; idx += 512) {
    int r = idx >> 4, o = idx & 15;
    wout_sh[r * 17 + o] = w_out[(size_t)(1 + dir * HH + row0 + r) * OO + o];
  }
  // finalize-thread state: rows r0 and r0+32, chain ch
  const int ch = tid & 15;
  const int r0 = tid >> 4;            // 0..31
  const float bias0 = w_bias[row0 + r0];
  const float bias1 = w_bias[row0 + r0 + 32];
  float hp0 = 0.f, hp1 = 0.f;

  for (int idx = tid; idx < HH; idx += 512) { z_sh[idx] = 0.f; }
  __syncthreads();

  unsigned tgt = 0;
#pragma unroll 1
  for (int i = 0; i < STEPS; ++i) {
    const int par = i & 1;
    const size_t hbase = ((size_t)(grp * 2 + par) * KCH + lm) * HH;

    // ---- B fragments (plain loads; barrier's acquire fence invalidated caches)
    uint4 Bh[2], Bl[2];
    {
      const int k = (rg * 4) * 32 + l4 * 8;
      Bh[0] = *(const uint4*)(hhi + hbase + k);
      Bl[0] = *(const uint4*)(hlo + hbase + k);
    }
    // u fragment (waves 0,1)
    uint4 uBh, uBl;
    if (rg < 2) {
      int ts = lm * CHUNK - WASH; if (ts < 0) ts = 0;
      int tau = ts + i;
      int t = dir ? (TT - 1 - tau) : tau;
      size_t ub = ((size_t)(b * TT + t)) * DD + rg * 32 + l4 * 8;
      uBh = *(const uint4*)(uhi + ub);
      uBl = *(const uint4*)(ulo + ub);
    }

    f32x4 acc[4];
#pragma unroll
    for (int mt = 0; mt < 4; ++mt) acc[mt] = (f32x4){0.f, 0.f, 0.f, 0.f};

#pragma unroll
    for (int kt = 0; kt < 4; ++kt) {
      if (kt < 3) {   // prefetch next k-tile into the other buffer
        const int k = (rg * 4 + kt + 1) * 32 + l4 * 8;
        Bh[(kt + 1) & 1] = *(const uint4*)(hhi + hbase + k);
        Bl[(kt + 1) & 1] = *(const uint4*)(hlo + hbase + k);
      }
      short8 bh = *(short8*)&Bh[kt & 1];
      short8 bl = *(short8*)&Bl[kt & 1];
#pragma unroll
      for (int mt = 0; mt < 4; ++mt) {
        acc[mt] = __builtin_amdgcn_mfma_f32_16x16x32_bf16(Ahi[mt][kt], bh, acc[mt], 0, 0, 0);
        acc[mt] = __builtin_amdgcn_mfma_f32_16x16x32_bf16(Ahi[mt][kt], bl, acc[mt], 0, 0, 0);
        acc[mt] = __builtin_amdgcn_mfma_f32_16x16x32_bf16(Alo[mt][kt], bh, acc[mt], 0, 0, 0);
      }
    }
    if (rg < 2) {
      short8 ubh = *(short8*)&uBh;
      short8 ubl = *(short8*)&uBl;
#pragma unroll
      for (int mt = 0; mt < 4; ++mt) {
        acc[mt] = __builtin_amdgcn_mfma_f32_16x16x32_bf16(UAhi[mt], ubh, acc[mt], 0, 0, 0);
        acc[mt] = __builtin_amdgcn_mfma_f32_16x16x32_bf16(UAhi[mt], ubl, acc[mt], 0, 0, 0);
        acc[mt] = __builtin_amdgcn_mfma_f32_16x16x32_bf16(UAlo[mt], ubh, acc[mt], 0, 0, 0);
      }
    }

    // ---- cross-wave K reduction: C layout is row=(l>>4)*4+j, col=lm
#pragma unroll
    for (int mt = 0; mt < 4; ++mt)
#pragma unroll
      for (int j = 0; j < 4; ++j)
        atomicAdd(&z_sh[zidx(mt * 16 + l4 * 4 + j, lm)], acc[mt][j]);
    __syncthreads();

    // ---- finalize: 2 (row,chain) elems per thread
    {
      const int zi0 = zidx(r0, ch), zi1 = zidx(r0 + 32, ch);
      float z0 = z_sh[zi0] + bias0;
      float z1 = z_sh[zi1] + bias1;
      z_sh[zi0] = 0.f; z_sh[zi1] = 0.f;   // re-zero for next step
      float e0 = __expf(2.0f * z0);
      float e1 = __expf(2.0f * z1);
      float th0 = 1.0f - 2.0f * __builtin_amdgcn_rcpf(e0 + 1.0f);
      float th1 = 1.0f - 2.0f * __builtin_amdgcn_rcpf(e1 + 1.0f);
      hp0 = 0.1f * hp0 + 0.9f * th0;
      hp1 = 0.1f * hp1 + 0.9f * th1;
      hn_sh[hidx(r0, ch)] = hp0;
      hn_sh[hidx(r0 + 32, ch)] = hp1;
      // publish h (bf16 hi/lo) for next step, device-coherent
      const size_t ho = ((size_t)(grp * 2 + (par ^ 1)) * KCH + ch) * HH + row0;
      unsigned short h0h = f2bf(hp0), h0l = f2bf(hp0 - bf2f(h0h));
      unsigned short h1h = f2bf(hp1), h1l = f2bf(hp1 - bf2f(h1h));
      __hip_atomic_store(hhi + ho + r0, h0h, __ATOMIC_RELAXED, __HIP_MEMORY_SCOPE_AGENT);
      __hip_atomic_store(hlo + ho + r0, h0l, __ATOMIC_RELAXED, __HIP_MEMORY_SCOPE_AGENT);
      __hip_atomic_store(hhi + ho + r0 + 32, h1h, __ATOMIC_RELAXED, __HIP_MEMORY_SCOPE_AGENT);
      __hip_atomic_store(hlo + ho + r0 + 32, h1l, __ATOMIC_RELAXED, __HIP_MEMORY_SCOPE_AGENT);
    }
    __syncthreads();

    // ---- readout partials: 2 chains per wave, inside useful window only
#pragma unroll
    for (int cidx = 0; cidx < 2; ++cidx) {
      int cc = rg * 2 + cidx;
      int ts = cc * CHUNK - WASH; if (ts < 0) ts = 0;
      int tau = ts + i;
      int rel = tau - cc * CHUNK;
      if (rel >= 0 && rel < CHUNK) {
        int t_out = dir ? (TT - 1 - tau) : tau;
        float s = 0.f;
#pragma unroll
        for (int j = 0; j < 16; ++j)
          s += hn_sh[hidx(l4 * 16 + j, cc)] * wout_sh[(l4 * 16 + j) * 17 + lm];
        s += __shfl_xor(s, 16);
        s += __shfl_xor(s, 32);
        if (lane < 16)
          partial[((size_t)(grp * GBLK + blk) * TT + t_out) * OO + lm] = s;
      }
    }

    // ---- group barrier: release flag, wave 0 polls 16 flags, acquire fence
    tgt++;
    __syncthreads();
    if (tid == 0)
      __hip_atomic_store(flags + blk, tgt, __ATOMIC_RELEASE, __HIP_MEMORY_SCOPE_AGENT);
    if (tid < 64) {
      while (true) {
        unsigned v = __hip_atomic_load(flags + (lane & 15),
                                       __ATOMIC_RELAXED, __HIP_MEMORY_SCOPE_AGENT);
        if (__all(v >= tgt)) break;
        __builtin_amdgcn_s_sleep(1);
      }
      __threadfence();   // agent acquire: invalidate L1 + XCD L2
    }
    __syncthreads();
  }
}

__global__ __launch_bounds__(256) void combine_kernel(
    const float* __restrict__ w_out, const float* __restrict__ partial,
    float* __restrict__ out)
{
  int idx = blockIdx.x * 256 + threadIdx.x;   // (b*2048+t)*16+o
  int o = idx & 15;
  int bt = idx >> 4;
  int b_ = bt >> 11;
  int t_ = bt & 2047;
  float s = w_out[o];   // bias row
#pragma unroll 1
  for (int dir = 0; dir < 2; ++dir)
#pragma unroll
    for (int g = 0; g < 16; ++g)
      s += partial[((size_t)((dir * 8 + b_) * 16 + g) * TT + t_) * OO + o];
  out[idx] = s;
}

extern "C" void kernel_launch(void* const* d_in, const int* in_sizes, int n_in,
                              void* d_out, int out_size, void* d_ws, size_t ws_size,
                              hipStream_t stream) {
  (void)in_sizes; (void)n_in; (void)out_size; (void)ws_size;
  const float* u      = (const float*)d_in[0];
  const float* w      = (const float*)d_in[1];
  const float* w_in   = (const float*)d_in[2];
  const float* w_bias = (const float*)d_in[3];
  const float* w_out  = (const float*)d_in[4];
  float* out = (float*)d_out;
  float* ws  = (float*)d_ws;

  // zero flags + h double buffers each replay
  hipMemsetAsync(d_ws, 0, (size_t)(1024 + 2 * 262144) * 4, stream);

  ucvt_kernel<<<dim3(1024), dim3(256), 0, stream>>>(
      u, (unsigned short*)(ws + WS_UHI), (unsigned short*)(ws + WS_ULO));
  esn_kernel<<<dim3(NGRP * GBLK), dim3(512), 0, stream>>>(w, w_in, w_bias, w_out, ws);
  combine_kernel<<<dim3((BB * TT * OO) / 256), dim3(256), 0, stream>>>(
      w_out, ws + WS_PART, out);
}

// Round 4
// 2622.490 us; speedup vs baseline: 2.8150x; 2.8150x over previous
//
#include <hip/hip_runtime.h>

#define BB 8
#define TT 2048
#define DD 64
#define HH 1024
#define OO 16
#define NGRP 16
#define GBLK 16
#define KCH 16
#define CHUNK 128
#define WASH 128
#define STEPS (CHUNK + WASH)   // 256

typedef __attribute__((ext_vector_type(8))) short short8;
typedef __attribute__((ext_vector_type(4))) float f32x4;

// ws layout (f32 units)
#define WS_HX   1024                    // [NGRP][2][KCH][HH] u32 (bf16 hi | lo<<16)
#define WS_UHI  (WS_HX + 524288)        // [BB][TT][DD] bf16
#define WS_ULO  (WS_UHI + 524288)
#define WS_PART (WS_ULO + 524288)       // [NGRP][GBLK][TT][OO] f32

__device__ __forceinline__ unsigned short f2bf(float x) {
  union { float f; unsigned u; } v; v.f = x;
  unsigned r = v.u + 0x7FFF + ((v.u >> 16) & 1);   // RNE
  return (unsigned short)(r >> 16);
}
__device__ __forceinline__ float bf2f(unsigned short h) {
  union { unsigned u; float f; } v; v.u = ((unsigned)h) << 16; return v.f;
}

__global__ __launch_bounds__(256) void ucvt_kernel(const float* __restrict__ u,
    unsigned short* __restrict__ uhi, unsigned short* __restrict__ ulo) {
  int i = blockIdx.x * 256 + threadIdx.x;
  float4 v = ((const float4*)u)[i];
  ushort4 h, l;
  float x;
  x = v.x; h.x = f2bf(x); l.x = f2bf(x - bf2f(h.x));
  x = v.y; h.y = f2bf(x); l.y = f2bf(x - bf2f(h.y));
  x = v.z; h.z = f2bf(x); l.z = f2bf(x - bf2f(h.z));
  x = v.w; h.w = f2bf(x); l.w = f2bf(x - bf2f(h.w));
  ((ushort4*)uhi)[i] = h;
  ((ushort4*)ulo)[i] = l;
}

__global__ __launch_bounds__(512, 2) void esn_kernel(
    const float* __restrict__ w, const float* __restrict__ w_in,
    const float* __restrict__ w_bias, const float* __restrict__ w_out,
    float* __restrict__ ws)
{
  __shared__ float zp_sh[8 * 1088];   // [wave][row*17 + ch]
  __shared__ float hn_sh[64 * 17];    // [row*17 + ch]
  __shared__ float wout_sh[64 * 17];  // [row*17 + o]

  const int tid = threadIdx.x;
  const int lane = tid & 63;
  const int rg = tid >> 6;            // wave 0..7, owns k-slice [rg*128, rg*128+128)
  const int lm = lane & 15;
  const int l4 = lane >> 4;
  const int bid = blockIdx.x;
  const int grp = bid & 15;           // group = dir*8 + b; members ≡ grp mod 16
  const int blk = bid >> 4;           // block-in-group, owns rows [blk*64, blk*64+64)
  const int dir = grp >> 3;
  const int b = grp & 7;
  const int row0 = blk * 64;

  unsigned* flags = (unsigned*)ws + grp * 64;        // one 64B line per group
  unsigned* hx = (unsigned*)(ws + WS_HX);
  const unsigned short* uhi = (const unsigned short*)(ws + WS_UHI);
  const unsigned short* ulo = (const unsigned short*)(ws + WS_ULO);
  float* partial = ws + WS_PART;

  // ---- A fragments (split bf16): rows row0+mt*16+lm, k=(rg*4+kt)*32+l4*8+i
  short8 Ahi[4][4], Alo[4][4];
#pragma unroll
  for (int mt = 0; mt < 4; ++mt) {
#pragma unroll
    for (int kt = 0; kt < 4; ++kt) {
      const int row = row0 + mt * 16 + lm;
      const int kb = (rg * 4 + kt) * 32 + l4 * 8;
      const float* wp = w + (size_t)row * HH + kb;
      short8 h8, l8;
#pragma unroll
      for (int i2 = 0; i2 < 2; ++i2) {
        float4 v = ((const float4*)wp)[i2];
        float xs[4] = {v.x, v.y, v.z, v.w};
#pragma unroll
        for (int j = 0; j < 4; ++j) {
          unsigned short hb = f2bf(xs[j]);
          h8[i2 * 4 + j] = (short)hb;
          l8[i2 * 4 + j] = (short)f2bf(xs[j] - bf2f(hb));
        }
      }
      Ahi[mt][kt] = h8; Alo[mt][kt] = l8;
    }
  }
  short8 UAhi[4], UAlo[4];
  if (rg < 2) {
#pragma unroll
    for (int mt = 0; mt < 4; ++mt) {
      const int row = row0 + mt * 16 + lm;
      const int kb = rg * 32 + l4 * 8;
      const float* wp = w_in + (size_t)row * DD + kb;
      short8 h8, l8;
#pragma unroll
      for (int i2 = 0; i2 < 2; ++i2) {
        float4 v = ((const float4*)wp)[i2];
        float xs[4] = {v.x, v.y, v.z, v.w};
#pragma unroll
        for (int j = 0; j < 4; ++j) {
          unsigned short hb = f2bf(xs[j]);
          h8[i2 * 4 + j] = (short)hb;
          l8[i2 * 4 + j] = (short)f2bf(xs[j] - bf2f(hb));
        }
      }
      UAhi[mt] = h8; UAlo[mt] = l8;
    }
  }

  for (int idx = tid; idx < 1024; idx += 512) {
    int r = idx >> 4, o = idx & 15;
    wout_sh[r * 17 + o] = w_out[(size_t)(1 + dir * HH + row0 + r) * OO + o];
  }

  const int ch = tid & 15;
  const int r0 = tid >> 4;            // 0..31 -> rows r0, r0+32
  const float bias0 = w_bias[row0 + r0];
  const float bias1 = w_bias[row0 + r0 + 32];
  float hp0 = 0.f, hp1 = 0.f;
  __syncthreads();

#pragma unroll 1
  for (int i = 0; i < STEPS; ++i) {
    const int par = i & 1;
    const unsigned base_r = ((unsigned)(grp * 2 + par) * KCH + lm) * HH;

    // ---- B loads: device-scope relaxed u32 atomics (coherent at L3, no fences)
    unsigned bw[4][8];
#pragma unroll
    for (int kt = 0; kt < 4; ++kt) {
      const int kb = (rg * 4 + kt) * 32 + l4 * 8;
#pragma unroll
      for (int j = 0; j < 8; ++j)
        bw[kt][j] = __hip_atomic_load(hx + base_r + kb + j,
                                      __ATOMIC_RELAXED, __HIP_MEMORY_SCOPE_AGENT);
    }
    uint4 uh4, ul4;
    if (rg < 2) {
      int ts = lm * CHUNK - WASH; if (ts < 0) ts = 0;
      int tau = ts + i;
      int t = dir ? (TT - 1 - tau) : tau;
      size_t ub = ((size_t)(b * TT + t)) * DD + rg * 32 + l4 * 8;
      uh4 = *(const uint4*)(uhi + ub);
      ul4 = *(const uint4*)(ulo + ub);
    }

    f32x4 acc[4];
#pragma unroll
    for (int mt = 0; mt < 4; ++mt) acc[mt] = (f32x4){0.f, 0.f, 0.f, 0.f};

#pragma unroll
    for (int kt = 0; kt < 4; ++kt) {
      uint4 vh, vl;
      vh.x = (bw[kt][0] & 0xFFFFu) | (bw[kt][1] << 16);
      vh.y = (bw[kt][2] & 0xFFFFu) | (bw[kt][3] << 16);
      vh.z = (bw[kt][4] & 0xFFFFu) | (bw[kt][5] << 16);
      vh.w = (bw[kt][6] & 0xFFFFu) | (bw[kt][7] << 16);
      vl.x = (bw[kt][0] >> 16) | (bw[kt][1] & 0xFFFF0000u);
      vl.y = (bw[kt][2] >> 16) | (bw[kt][3] & 0xFFFF0000u);
      vl.z = (bw[kt][4] >> 16) | (bw[kt][5] & 0xFFFF0000u);
      vl.w = (bw[kt][6] >> 16) | (bw[kt][7] & 0xFFFF0000u);
      short8 bh = *(short8*)&vh;
      short8 bl = *(short8*)&vl;
#pragma unroll
      for (int mt = 0; mt < 4; ++mt) {
        acc[mt] = __builtin_amdgcn_mfma_f32_16x16x32_bf16(Ahi[mt][kt], bh, acc[mt], 0, 0, 0);
        acc[mt] = __builtin_amdgcn_mfma_f32_16x16x32_bf16(Ahi[mt][kt], bl, acc[mt], 0, 0, 0);
        acc[mt] = __builtin_amdgcn_mfma_f32_16x16x32_bf16(Alo[mt][kt], bh, acc[mt], 0, 0, 0);
      }
    }
    if (rg < 2) {
      short8 ubh = *(short8*)&uh4;
      short8 ubl = *(short8*)&ul4;
#pragma unroll
      for (int mt = 0; mt < 4; ++mt) {
        acc[mt] = __builtin_amdgcn_mfma_f32_16x16x32_bf16(UAhi[mt], ubh, acc[mt], 0, 0, 0);
        acc[mt] = __builtin_amdgcn_mfma_f32_16x16x32_bf16(UAhi[mt], ubl, acc[mt], 0, 0, 0);
        acc[mt] = __builtin_amdgcn_mfma_f32_16x16x32_bf16(UAlo[mt], ubh, acc[mt], 0, 0, 0);
      }
    }

    // ---- per-wave K-partials to LDS (plain writes, no atomics)
#pragma unroll
    for (int mt = 0; mt < 4; ++mt)
#pragma unroll
      for (int j = 0; j < 4; ++j)
        zp_sh[rg * 1088 + (mt * 16 + l4 * 4 + j) * 17 + lm] = acc[mt][j];
    __syncthreads();

    // ---- finalize: rows r0, r0+32 of chain ch
    float z0 = bias0, z1 = bias1;
#pragma unroll
    for (int g2 = 0; g2 < 8; ++g2) {
      z0 += zp_sh[g2 * 1088 + r0 * 17 + ch];
      z1 += zp_sh[g2 * 1088 + (r0 + 32) * 17 + ch];
    }
    float e0 = __expf(2.0f * z0), e1 = __expf(2.0f * z1);
    float th0 = 1.0f - 2.0f * __builtin_amdgcn_rcpf(e0 + 1.0f);
    float th1 = 1.0f - 2.0f * __builtin_amdgcn_rcpf(e1 + 1.0f);
    hp0 = 0.1f * hp0 + 0.9f * th0;
    hp1 = 0.1f * hp1 + 0.9f * th1;
    hn_sh[r0 * 17 + ch] = hp0;
    hn_sh[(r0 + 32) * 17 + ch] = hp1;
    unsigned short h0h = f2bf(hp0);
    unsigned short h1h = f2bf(hp1);
    unsigned p0 = (unsigned)h0h | ((unsigned)f2bf(hp0 - bf2f(h0h)) << 16);
    unsigned p1 = (unsigned)h1h | ((unsigned)f2bf(hp1 - bf2f(h1h)) << 16);
    const unsigned ho = ((unsigned)(grp * 2 + (par ^ 1)) * KCH + ch) * HH + row0;
    __hip_atomic_store(hx + ho + r0, p0, __ATOMIC_RELAXED, __HIP_MEMORY_SCOPE_AGENT);
    __hip_atomic_store(hx + ho + r0 + 32, p1, __ATOMIC_RELAXED, __HIP_MEMORY_SCOPE_AGENT);
    asm volatile("s_waitcnt vmcnt(0)" ::: "memory");   // h stores at coherence point
    __syncthreads();
    if (tid == 0)
      __hip_atomic_store(flags + blk, (unsigned)(i + 1),
                         __ATOMIC_RELAXED, __HIP_MEMORY_SCOPE_AGENT);

    // ---- readout partials while flag propagates
#pragma unroll
    for (int cidx = 0; cidx < 2; ++cidx) {
      int cc = rg * 2 + cidx;
      int ts = cc * CHUNK - WASH; if (ts < 0) ts = 0;
      int tau = ts + i;
      int rel = tau - cc * CHUNK;
      if (rel >= 0 && rel < CHUNK) {
        int t_out = dir ? (TT - 1 - tau) : tau;
        float s = 0.f;
#pragma unroll
        for (int j = 0; j < 16; ++j)
          s += hn_sh[(l4 * 16 + j) * 17 + cc] * wout_sh[(l4 * 16 + j) * 17 + lm];
        s += __shfl_xor(s, 16);
        s += __shfl_xor(s, 32);
        if (lane < 16)
          partial[((size_t)(grp * GBLK + blk) * TT + t_out) * OO + lm] = s;
      }
    }

    // ---- all-wave poll (no trailing barrier needed; see hazard analysis)
    if (i + 1 < STEPS) {
      const unsigned tg = (unsigned)(i + 1);
      while (true) {
        unsigned v = __hip_atomic_load(flags + lm, __ATOMIC_RELAXED,
                                       __HIP_MEMORY_SCOPE_AGENT);
        if (__all(v >= tg)) break;
        __builtin_amdgcn_s_sleep(1);
      }
      asm volatile("" ::: "memory");   // keep next-step h loads after the poll
    }
  }
}

__global__ __launch_bounds__(256) void combine_kernel(
    const float* __restrict__ w_out, const float* __restrict__ partial,
    float* __restrict__ out)
{
  int idx = blockIdx.x * 256 + threadIdx.x;   // (b*2048+t)*16+o
  int o = idx & 15;
  int bt = idx >> 4;
  int b_ = bt >> 11;
  int t_ = bt & 2047;
  float s = w_out[o];   // bias row
#pragma unroll 1
  for (int dir = 0; dir < 2; ++dir)
#pragma unroll
    for (int g = 0; g < 16; ++g)
      s += partial[((size_t)((dir * 8 + b_) * 16 + g) * TT + t_) * OO + o];
  out[idx] = s;
}

extern "C" void kernel_launch(void* const* d_in, const int* in_sizes, int n_in,
                              void* d_out, int out_size, void* d_ws, size_t ws_size,
                              hipStream_t stream) {
  (void)in_sizes; (void)n_in; (void)out_size; (void)ws_size;
  const float* u      = (const float*)d_in[0];
  const float* w      = (const float*)d_in[1];
  const float* w_in   = (const float*)d_in[2];
  const float* w_bias = (const float*)d_in[3];
  const float* w_out  = (const float*)d_in[4];
  float* out = (float*)d_out;
  float* ws  = (float*)d_ws;

  // zero flags + packed h double buffers each replay
  hipMemsetAsync(d_ws, 0, (size_t)(WS_HX + 524288) * 4, stream);

  ucvt_kernel<<<dim3(1024), dim3(256), 0, stream>>>(
      u, (unsigned short*)(ws + WS_UHI), (unsigned short*)(ws + WS_ULO));
  esn_kernel<<<dim3(NGRP * GBLK), dim3(512), 0, stream>>>(w, w_in, w_bias, w_out, ws);
  combine_kernel<<<dim3((BB * TT * OO) / 256), dim3(256), 0, stream>>>(
      w_out, ws + WS_PART, out);
}

// Round 6
// 1078.073 us; speedup vs baseline: 6.8476x; 2.4326x over previous
//
#include <hip/hip_runtime.h>

#define BB 8
#define TT 2048
#define DD 64
#define HH 1024
#define OO 16
#define NGRP 16
#define GBLK 16
#define KCH 16
#define CHUNK 128
#define WASH 96
#define STEPS (CHUNK + WASH)   // 224

typedef __attribute__((ext_vector_type(8))) short short8;
typedef __attribute__((ext_vector_type(4))) float f32x4;

// ws layout (f32 units)
#define WS_HX   1024                    // [NGRP][2][KCH][HH] u32 (bf16 hi | lo<<16)
#define WS_UHI  (WS_HX + 524288)        // [BB][TT][DD] bf16
#define WS_ULO  (WS_UHI + 524288)
#define WS_PART (WS_ULO + 524288)       // [NGRP][GBLK][TT][OO] f32

__device__ __forceinline__ unsigned short f2bf(float x) {
  union { float f; unsigned u; } v; v.f = x;
  unsigned r = v.u + 0x7FFF + ((v.u >> 16) & 1);   // RNE
  return (unsigned short)(r >> 16);
}
__device__ __forceinline__ float bf2f(unsigned short h) {
  union { unsigned u; float f; } v; v.u = ((unsigned)h) << 16; return v.f;
}

// device-coherent 16B load (bypasses stale L1/L2 copies, like agent-scope atomics)
__device__ __forceinline__ uint4 ld_cohx4(const unsigned* p) {
  uint4 r;
  asm volatile("global_load_dwordx4 %0, %1, off sc0 sc1" : "=&v"(r) : "v"(p));
  return r;
}

__global__ __launch_bounds__(256) void ucvt_kernel(const float* __restrict__ u,
    unsigned short* __restrict__ uhi, unsigned short* __restrict__ ulo) {
  int i = blockIdx.x * 256 + threadIdx.x;
  float4 v = ((const float4*)u)[i];
  ushort4 h, l;
  float x;
  x = v.x; h.x = f2bf(x); l.x = f2bf(x - bf2f(h.x));
  x = v.y; h.y = f2bf(x); l.y = f2bf(x - bf2f(h.y));
  x = v.z; h.z = f2bf(x); l.z = f2bf(x - bf2f(h.z));
  x = v.w; h.w = f2bf(x); l.w = f2bf(x - bf2f(h.w));
  ((ushort4*)uhi)[i] = h;
  ((ushort4*)ulo)[i] = l;
}

__global__ __launch_bounds__(512, 2) void esn_kernel(
    const float* __restrict__ w, const float* __restrict__ w_in,
    const float* __restrict__ w_bias, const float* __restrict__ w_out,
    float* __restrict__ ws)
{
  __shared__ float zp_sh[8 * 1088];   // [wave][row*17 + ch]
  __shared__ float hn_sh[64 * 17];    // [row*17 + ch]
  __shared__ float wout_sh[64 * 17];  // [row*17 + o]

  const int tid = threadIdx.x;
  const int lane = tid & 63;
  const int rg = tid >> 6;            // wave 0..7, owns k-slice [rg*128, rg*128+128)
  const int lm = lane & 15;
  const int l4 = lane >> 4;
  const int bid = blockIdx.x;
  const int grp = bid & 15;           // group = dir*8 + b; members ≡ grp mod 16
  const int blk = bid >> 4;           // owns rows [blk*64, blk*64+64)
  const int dir = grp >> 3;
  const int b = grp & 7;
  const int row0 = blk * 64;

  unsigned* flags = (unsigned*)ws + grp * 64;
  unsigned* hx = (unsigned*)(ws + WS_HX);
  const unsigned short* uhi = (const unsigned short*)(ws + WS_UHI);
  const unsigned short* ulo = (const unsigned short*)(ws + WS_ULO);
  float* partial = ws + WS_PART;

  // ---- A fragments (split bf16): rows row0+mt*16+lm, k=(rg*4+kt)*32+l4*8+i
  short8 Ahi[4][4], Alo[4][4];
#pragma unroll
  for (int mt = 0; mt < 4; ++mt) {
#pragma unroll
    for (int kt = 0; kt < 4; ++kt) {
      const int row = row0 + mt * 16 + lm;
      const int kb = (rg * 4 + kt) * 32 + l4 * 8;
      const float* wp = w + (size_t)row * HH + kb;
      short8 h8, l8;
#pragma unroll
      for (int i2 = 0; i2 < 2; ++i2) {
        float4 v = ((const float4*)wp)[i2];
        float xs[4] = {v.x, v.y, v.z, v.w};
#pragma unroll
        for (int j = 0; j < 4; ++j) {
          unsigned short hb = f2bf(xs[j]);
          h8[i2 * 4 + j] = (short)hb;
          l8[i2 * 4 + j] = (short)f2bf(xs[j] - bf2f(hb));
        }
      }
      Ahi[mt][kt] = h8; Alo[mt][kt] = l8;
    }
  }
  short8 UAhi[4], UAlo[4];
  if (rg < 2) {
#pragma unroll
    for (int mt = 0; mt < 4; ++mt) {
      const int row = row0 + mt * 16 + lm;
      const int kb = rg * 32 + l4 * 8;
      const float* wp = w_in + (size_t)row * DD + kb;
      short8 h8, l8;
#pragma unroll
      for (int i2 = 0; i2 < 2; ++i2) {
        float4 v = ((const float4*)wp)[i2];
        float xs[4] = {v.x, v.y, v.z, v.w};
#pragma unroll
        for (int j = 0; j < 4; ++j) {
          unsigned short hb = f2bf(xs[j]);
          h8[i2 * 4 + j] = (short)hb;
          l8[i2 * 4 + j] = (short)f2bf(xs[j] - bf2f(hb));
        }
      }
      UAhi[mt] = h8; UAlo[mt] = l8;
    }
  }

  for (int idx = tid; idx < 1024; idx += 512) {
    int r = idx >> 4, o = idx & 15;
    wout_sh[r * 17 + o] = w_out[(size_t)(1 + dir * HH + row0 + r) * OO + o];
  }

  // finalize mapping: thread -> chain ch, adjacent rows 2q2, 2q2+1
  const int ch = tid & 15;
  const int q2 = tid >> 4;            // 0..31
  const float bias0 = w_bias[row0 + 2 * q2];
  const float bias1 = w_bias[row0 + 2 * q2 + 1];
  float hp0 = 0.f, hp1 = 0.f;
  __syncthreads();

#pragma unroll 1
  for (int i = 0; i < STEPS; ++i) {
    const int par = i & 1;
    const unsigned* hb_r = hx + ((unsigned)(grp * 2 + par) * KCH + lm) * HH;

    // ---- B loads: 8 coherent dwordx4 (vs 32 dword atomics)
    uint4 B0[4], B1[4];
#pragma unroll
    for (int kt = 0; kt < 4; ++kt) {
      const unsigned* p = hb_r + (rg * 4 + kt) * 32 + l4 * 8;
      B0[kt] = ld_cohx4(p);
      B1[kt] = ld_cohx4(p + 4);
    }
    uint4 uh4, ul4;
    if (rg < 2) {
      int ts = lm * CHUNK - WASH; if (ts < 0) ts = 0;
      int tau = ts + i;
      int t = dir ? (TT - 1 - tau) : tau;
      size_t ub = ((size_t)(b * TT + t)) * DD + rg * 32 + l4 * 8;
      uh4 = *(const uint4*)(uhi + ub);
      ul4 = *(const uint4*)(ulo + ub);
    }
    // batched wait; sched_barrier stops register-only unpack from hoisting above
    asm volatile("s_waitcnt vmcnt(0)" ::: "memory");
    __builtin_amdgcn_sched_barrier(0);

    f32x4 acc[4];
#pragma unroll
    for (int mt = 0; mt < 4; ++mt) acc[mt] = (f32x4){0.f, 0.f, 0.f, 0.f};

#pragma unroll
    for (int kt = 0; kt < 4; ++kt) {
      const unsigned b0 = B0[kt].x, b1 = B0[kt].y, b2 = B0[kt].z, b3 = B0[kt].w;
      const unsigned b4 = B1[kt].x, b5 = B1[kt].y, b6 = B1[kt].z, b7 = B1[kt].w;
      uint4 vh, vl;
      vh.x = (b0 & 0xFFFFu) | (b1 << 16);
      vh.y = (b2 & 0xFFFFu) | (b3 << 16);
      vh.z = (b4 & 0xFFFFu) | (b5 << 16);
      vh.w = (b6 & 0xFFFFu) | (b7 << 16);
      vl.x = (b0 >> 16) | (b1 & 0xFFFF0000u);
      vl.y = (b2 >> 16) | (b3 & 0xFFFF0000u);
      vl.z = (b4 >> 16) | (b5 & 0xFFFF0000u);
      vl.w = (b6 >> 16) | (b7 & 0xFFFF0000u);
      short8 bh = *(short8*)&vh;
      short8 bl = *(short8*)&vl;
#pragma unroll
      for (int mt = 0; mt < 4; ++mt) {
        acc[mt] = __builtin_amdgcn_mfma_f32_16x16x32_bf16(Ahi[mt][kt], bh, acc[mt], 0, 0, 0);
        acc[mt] = __builtin_amdgcn_mfma_f32_16x16x32_bf16(Ahi[mt][kt], bl, acc[mt], 0, 0, 0);
        acc[mt] = __builtin_amdgcn_mfma_f32_16x16x32_bf16(Alo[mt][kt], bh, acc[mt], 0, 0, 0);
      }
    }
    if (rg < 2) {
      short8 ubh = *(short8*)&uh4;
      short8 ubl = *(short8*)&ul4;
#pragma unroll
      for (int mt = 0; mt < 4; ++mt) {
        acc[mt] = __builtin_amdgcn_mfma_f32_16x16x32_bf16(UAhi[mt], ubh, acc[mt], 0, 0, 0);
        acc[mt] = __builtin_amdgcn_mfma_f32_16x16x32_bf16(UAhi[mt], ubl, acc[mt], 0, 0, 0);
        acc[mt] = __builtin_amdgcn_mfma_f32_16x16x32_bf16(UAlo[mt], ubh, acc[mt], 0, 0, 0);
      }
    }

    // ---- per-wave K-partials to LDS
#pragma unroll
    for (int mt = 0; mt < 4; ++mt)
#pragma unroll
      for (int j = 0; j < 4; ++j)
        zp_sh[rg * 1088 + (mt * 16 + l4 * 4 + j) * 17 + lm] = acc[mt][j];
    __syncthreads();

    // ---- finalize rows 2q2, 2q2+1 of chain ch
    float z0 = bias0, z1 = bias1;
#pragma unroll
    for (int g2 = 0; g2 < 8; ++g2) {
      z0 += zp_sh[g2 * 1088 + (2 * q2) * 17 + ch];
      z1 += zp_sh[g2 * 1088 + (2 * q2 + 1) * 17 + ch];
    }
    float e0 = __expf(2.0f * z0), e1 = __expf(2.0f * z1);
    float th0 = 1.0f - 2.0f * __builtin_amdgcn_rcpf(e0 + 1.0f);
    float th1 = 1.0f - 2.0f * __builtin_amdgcn_rcpf(e1 + 1.0f);
    hp0 = 0.1f * hp0 + 0.9f * th0;
    hp1 = 0.1f * hp1 + 0.9f * th1;
    hn_sh[(2 * q2) * 17 + ch] = hp0;
    hn_sh[(2 * q2 + 1) * 17 + ch] = hp1;
    unsigned short h0h = f2bf(hp0);
    unsigned short h1h = f2bf(hp1);
    unsigned p0 = (unsigned)h0h | ((unsigned)f2bf(hp0 - bf2f(h0h)) << 16);
    unsigned p1 = (unsigned)h1h | ((unsigned)f2bf(hp1 - bf2f(h1h)) << 16);
    unsigned long long pv = (unsigned long long)p0 | ((unsigned long long)p1 << 32);
    const unsigned ho = ((unsigned)(grp * 2 + (par ^ 1)) * KCH + ch) * HH + row0 + 2 * q2;
    __hip_atomic_store((unsigned long long*)(hx + ho), pv,
                       __ATOMIC_RELAXED, __HIP_MEMORY_SCOPE_AGENT);
    asm volatile("s_waitcnt vmcnt(0)" ::: "memory");   // h at coherence point
    __syncthreads();
    if (tid == 0)
      __hip_atomic_store(flags + blk, (unsigned)(i + 1),
                         __ATOMIC_RELAXED, __HIP_MEMORY_SCOPE_AGENT);

    // ---- readout partials while flag propagates
#pragma unroll
    for (int cidx = 0; cidx < 2; ++cidx) {
      int cc = rg * 2 + cidx;
      int ts = cc * CHUNK - WASH; if (ts < 0) ts = 0;
      int tau = ts + i;
      int rel = tau - cc * CHUNK;
      if (rel >= 0 && rel < CHUNK) {
        int t_out = dir ? (TT - 1 - tau) : tau;
        float s = 0.f;
#pragma unroll
        for (int j = 0; j < 16; ++j)
          s += hn_sh[(l4 * 16 + j) * 17 + cc] * wout_sh[(l4 * 16 + j) * 17 + lm];
        s += __shfl_xor(s, 16);
        s += __shfl_xor(s, 32);
        if (lane < 16)
          partial[((size_t)(grp * GBLK + blk) * TT + t_out) * OO + lm] = s;
      }
    }

    // ---- single-wave poll, barrier release
    if (i + 1 < STEPS) {
      if (tid < 64) {
        const unsigned tg = (unsigned)(i + 1);
        unsigned v;
        do {
          v = __hip_atomic_load(flags + (lane & 15), __ATOMIC_RELAXED,
                                __HIP_MEMORY_SCOPE_AGENT);
        } while (!__all(v >= tg));
        asm volatile("" ::: "memory");
      }
      __syncthreads();
    }
  }
}

__global__ __launch_bounds__(256) void combine_kernel(
    const float* __restrict__ w_out, const float* __restrict__ partial,
    float* __restrict__ out)
{
  int idx = blockIdx.x * 256 + threadIdx.x;   // (b*2048+t)*16+o
  int o = idx & 15;
  int bt = idx >> 4;
  int b_ = bt >> 11;
  int t_ = bt & 2047;
  float s = w_out[o];   // bias row
#pragma unroll 1
  for (int dir = 0; dir < 2; ++dir)
#pragma unroll
    for (int g = 0; g < 16; ++g)
      s += partial[((size_t)((dir * 8 + b_) * 16 + g) * TT + t_) * OO + o];
  out[idx] = s;
}

extern "C" void kernel_launch(void* const* d_in, const int* in_sizes, int n_in,
                              void* d_out, int out_size, void* d_ws, size_t ws_size,
                              hipStream_t stream) {
  (void)in_sizes; (void)n_in; (void)out_size; (void)ws_size;
  const float* u      = (const float*)d_in[0];
  const float* w      = (const float*)d_in[1];
  const float* w_in   = (const float*)d_in[2];
  const float* w_bias = (const float*)d_in[3];
  const float* w_out  = (const float*)d_in[4];
  float* out = (float*)d_out;
  float* ws  = (float*)d_ws;

  // zero flags + packed h double buffers each replay
  (void)hipMemsetAsync(d_ws, 0, (size_t)(WS_HX + 524288) * 4, stream);

  ucvt_kernel<<<dim3(1024), dim3(256), 0, stream>>>(
      u, (unsigned short*)(ws + WS_UHI), (unsigned short*)(ws + WS_ULO));
  esn_kernel<<<dim3(NGRP * GBLK), dim3(512), 0, stream>>>(w, w_in, w_bias, w_out, ws);
  combine_kernel<<<dim3((BB * TT * OO) / 256), dim3(256), 0, stream>>>(
      w_out, ws + WS_PART, out);
}

// Round 7
// 896.459 us; speedup vs baseline: 8.2349x; 1.2026x over previous
//
#include <hip/hip_runtime.h>

#define BB 8
#define TT 2048
#define DD 64
#define HH 1024
#define OO 16
#define NGRP 16
#define GBLK 16
#define KCH 16
#define CHUNK 128
#define WASH 64
#define STEPS (CHUNK + WASH)   // 192

typedef __attribute__((ext_vector_type(8))) short short8;
typedef __attribute__((ext_vector_type(4))) float f32x4;

// ws layout (f32 units)
#define WS_HX   8192                    // flags: [NGRP][GBLK] u32, 128B apart
#define WS_UHI  (WS_HX + 524288)        // hx: [NGRP][2][KCH][HH] u32 (bf16 hi|lo<<16)
#define WS_ULO  (WS_UHI + 524288)
#define WS_PART (WS_ULO + 524288)       // [NGRP][GBLK][TT][OO] f32

__device__ __forceinline__ unsigned short f2bf(float x) {
  union { float f; unsigned u; } v; v.f = x;
  unsigned r = v.u + 0x7FFF + ((v.u >> 16) & 1);   // RNE
  return (unsigned short)(r >> 16);
}
__device__ __forceinline__ float bf2f(unsigned short h) {
  union { unsigned u; float f; } v; v.u = ((unsigned)h) << 16; return v.f;
}

// device-coherent 16B load (reads the coherence point, like agent-scope atomics)
__device__ __forceinline__ uint4 ld_cohx4(const unsigned* p) {
  uint4 r;
  asm volatile("global_load_dwordx4 %0, %1, off sc0 sc1" : "=&v"(r) : "v"(p));
  return r;
}

__global__ __launch_bounds__(256) void ucvt_kernel(const float* __restrict__ u,
    unsigned short* __restrict__ uhi, unsigned short* __restrict__ ulo) {
  int i = blockIdx.x * 256 + threadIdx.x;
  float4 v = ((const float4*)u)[i];
  ushort4 h, l;
  float x;
  x = v.x; h.x = f2bf(x); l.x = f2bf(x - bf2f(h.x));
  x = v.y; h.y = f2bf(x); l.y = f2bf(x - bf2f(h.y));
  x = v.z; h.z = f2bf(x); l.z = f2bf(x - bf2f(h.z));
  x = v.w; h.w = f2bf(x); l.w = f2bf(x - bf2f(h.w));
  ((ushort4*)uhi)[i] = h;
  ((ushort4*)ulo)[i] = l;
}

__global__ __launch_bounds__(512, 2) void esn_kernel(
    const float* __restrict__ w, const float* __restrict__ w_in,
    const float* __restrict__ w_bias, const float* __restrict__ w_out,
    float* __restrict__ ws)
{
  __shared__ float zp_sh[8 * 1088];   // [wave][row*17 + ch]
  __shared__ float hn_sh[64 * 17];    // [row*17 + ch]
  __shared__ float wout_sh[64 * 17];  // [row*17 + o]

  const int tid = threadIdx.x;
  const int lane = tid & 63;
  const int rg = tid >> 6;            // wave 0..7, owns k-slice [rg*128, rg*128+128)
  const int lm = lane & 15;
  const int l4 = lane >> 4;
  const int bid = blockIdx.x;
  const int grp = bid & 15;           // group = dir*8 + b
  const int blk = bid >> 4;           // owns rows [blk*64, blk*64+64)
  const int dir = grp >> 3;
  const int b = grp & 7;
  const int row0 = blk * 64;

  unsigned* flags = (unsigned*)ws;    // flag(grp,blk) at (grp*16+blk)*32, own line
  unsigned* hx = (unsigned*)(ws + WS_HX);
  const unsigned short* uhi = (const unsigned short*)(ws + WS_UHI);
  const unsigned short* ulo = (const unsigned short*)(ws + WS_ULO);
  float* partial = ws + WS_PART;

  // ---- A fragments (split bf16): rows row0+mt*16+lm, k=(rg*4+kt)*32+l4*8+i
  short8 Ahi[4][4], Alo[4][4];
#pragma unroll
  for (int mt = 0; mt < 4; ++mt) {
#pragma unroll
    for (int kt = 0; kt < 4; ++kt) {
      const int row = row0 + mt * 16 + lm;
      const int kb = (rg * 4 + kt) * 32 + l4 * 8;
      const float* wp = w + (size_t)row * HH + kb;
      short8 h8, l8;
#pragma unroll
      for (int i2 = 0; i2 < 2; ++i2) {
        float4 v = ((const float4*)wp)[i2];
        float xs[4] = {v.x, v.y, v.z, v.w};
#pragma unroll
        for (int j = 0; j < 4; ++j) {
          unsigned short hb = f2bf(xs[j]);
          h8[i2 * 4 + j] = (short)hb;
          l8[i2 * 4 + j] = (short)f2bf(xs[j] - bf2f(hb));
        }
      }
      Ahi[mt][kt] = h8; Alo[mt][kt] = l8;
    }
  }
  short8 UAhi[4], UAlo[4];
  if (rg < 2) {
#pragma unroll
    for (int mt = 0; mt < 4; ++mt) {
      const int row = row0 + mt * 16 + lm;
      const int kb = rg * 32 + l4 * 8;
      const float* wp = w_in + (size_t)row * DD + kb;
      short8 h8, l8;
#pragma unroll
      for (int i2 = 0; i2 < 2; ++i2) {
        float4 v = ((const float4*)wp)[i2];
        float xs[4] = {v.x, v.y, v.z, v.w};
#pragma unroll
        for (int j = 0; j < 4; ++j) {
          unsigned short hb = f2bf(xs[j]);
          h8[i2 * 4 + j] = (short)hb;
          l8[i2 * 4 + j] = (short)f2bf(xs[j] - bf2f(hb));
        }
      }
      UAhi[mt] = h8; UAlo[mt] = l8;
    }
  }

  for (int idx = tid; idx < 1024; idx += 512) {
    int r = idx >> 4, o = idx & 15;
    wout_sh[r * 17 + o] = w_out[(size_t)(1 + dir * HH + row0 + r) * OO + o];
  }

  // finalize mapping: thread -> chain ch, adjacent rows 2q2, 2q2+1
  const int ch = tid & 15;
  const int q2 = tid >> 4;            // 0..31
  const float bias0 = w_bias[row0 + 2 * q2];
  const float bias1 = w_bias[row0 + 2 * q2 + 1];
  float hp0 = 0.f, hp1 = 0.f;
  __syncthreads();

#pragma unroll 1
  for (int i = 0; i < STEPS; ++i) {
    const int par = i & 1;
    const unsigned* hb_r = hx + ((unsigned)(grp * 2 + par) * KCH + lm) * HH;

    // ---- per-wave producer-pair poll: wave rg needs only blocks 2rg, 2rg+1
    if (i > 0) {
      const unsigned tg = (unsigned)i;
      unsigned v;
      do {
        v = 0xFFFFFFFFu;
        if (lane < 2)
          v = __hip_atomic_load(flags + (grp * GBLK + 2 * rg + lane) * 32,
                                __ATOMIC_RELAXED, __HIP_MEMORY_SCOPE_AGENT);
      } while (!__all(v >= tg));
      asm volatile("" ::: "memory");
    }

    // ---- B loads: own k-slice, 8 coherent dwordx4
    uint4 B0[4], B1[4];
#pragma unroll
    for (int kt = 0; kt < 4; ++kt) {
      const unsigned* p = hb_r + (rg * 4 + kt) * 32 + l4 * 8;
      B0[kt] = ld_cohx4(p);
      B1[kt] = ld_cohx4(p + 4);
    }
    uint4 uh4, ul4;
    if (rg < 2) {
      int ts = lm * CHUNK - WASH; if (ts < 0) ts = 0;
      int tau = ts + i;
      int t = dir ? (TT - 1 - tau) : tau;
      size_t ub = ((size_t)(b * TT + t)) * DD + rg * 32 + l4 * 8;
      uh4 = *(const uint4*)(uhi + ub);
      ul4 = *(const uint4*)(ulo + ub);
    }
    asm volatile("s_waitcnt vmcnt(0)" ::: "memory");
    __builtin_amdgcn_sched_barrier(0);

    f32x4 acc[4];
#pragma unroll
    for (int mt = 0; mt < 4; ++mt) acc[mt] = (f32x4){0.f, 0.f, 0.f, 0.f};

#pragma unroll
    for (int kt = 0; kt < 4; ++kt) {
      const unsigned b0 = B0[kt].x, b1 = B0[kt].y, b2 = B0[kt].z, b3 = B0[kt].w;
      const unsigned b4 = B1[kt].x, b5 = B1[kt].y, b6 = B1[kt].z, b7 = B1[kt].w;
      uint4 vh, vl;
      vh.x = (b0 & 0xFFFFu) | (b1 << 16);
      vh.y = (b2 & 0xFFFFu) | (b3 << 16);
      vh.z = (b4 & 0xFFFFu) | (b5 << 16);
      vh.w = (b6 & 0xFFFFu) | (b7 << 16);
      vl.x = (b0 >> 16) | (b1 & 0xFFFF0000u);
      vl.y = (b2 >> 16) | (b3 & 0xFFFF0000u);
      vl.z = (b4 >> 16) | (b5 & 0xFFFF0000u);
      vl.w = (b6 >> 16) | (b7 & 0xFFFF0000u);
      short8 bh = *(short8*)&vh;
      short8 bl = *(short8*)&vl;
#pragma unroll
      for (int mt = 0; mt < 4; ++mt) {
        acc[mt] = __builtin_amdgcn_mfma_f32_16x16x32_bf16(Ahi[mt][kt], bh, acc[mt], 0, 0, 0);
        acc[mt] = __builtin_amdgcn_mfma_f32_16x16x32_bf16(Ahi[mt][kt], bl, acc[mt], 0, 0, 0);
        acc[mt] = __builtin_amdgcn_mfma_f32_16x16x32_bf16(Alo[mt][kt], bh, acc[mt], 0, 0, 0);
      }
    }
    if (rg < 2) {
      short8 ubh = *(short8*)&uh4;
      short8 ubl = *(short8*)&ul4;
#pragma unroll
      for (int mt = 0; mt < 4; ++mt) {
        acc[mt] = __builtin_amdgcn_mfma_f32_16x16x32_bf16(UAhi[mt], ubh, acc[mt], 0, 0, 0);
        acc[mt] = __builtin_amdgcn_mfma_f32_16x16x32_bf16(UAhi[mt], ubl, acc[mt], 0, 0, 0);
        acc[mt] = __builtin_amdgcn_mfma_f32_16x16x32_bf16(UAlo[mt], ubh, acc[mt], 0, 0, 0);
      }
    }

    // ---- per-wave K-partials to LDS
#pragma unroll
    for (int mt = 0; mt < 4; ++mt)
#pragma unroll
      for (int j = 0; j < 4; ++j)
        zp_sh[rg * 1088 + (mt * 16 + l4 * 4 + j) * 17 + lm] = acc[mt][j];
    __syncthreads();

    // ---- finalize rows 2q2, 2q2+1 of chain ch
    float z0 = bias0, z1 = bias1;
#pragma unroll
    for (int g2 = 0; g2 < 8; ++g2) {
      z0 += zp_sh[g2 * 1088 + (2 * q2) * 17 + ch];
      z1 += zp_sh[g2 * 1088 + (2 * q2 + 1) * 17 + ch];
    }
    float e0 = __expf(2.0f * z0), e1 = __expf(2.0f * z1);
    float th0 = 1.0f - 2.0f * __builtin_amdgcn_rcpf(e0 + 1.0f);
    float th1 = 1.0f - 2.0f * __builtin_amdgcn_rcpf(e1 + 1.0f);
    hp0 = 0.1f * hp0 + 0.9f * th0;
    hp1 = 0.1f * hp1 + 0.9f * th1;
    hn_sh[(2 * q2) * 17 + ch] = hp0;
    hn_sh[(2 * q2 + 1) * 17 + ch] = hp1;
    unsigned short h0h = f2bf(hp0);
    unsigned short h1h = f2bf(hp1);
    unsigned p0 = (unsigned)h0h | ((unsigned)f2bf(hp0 - bf2f(h0h)) << 16);
    unsigned p1 = (unsigned)h1h | ((unsigned)f2bf(hp1 - bf2f(h1h)) << 16);
    unsigned long long pv = (unsigned long long)p0 | ((unsigned long long)p1 << 32);
    const unsigned ho = ((unsigned)(grp * 2 + (par ^ 1)) * KCH + ch) * HH + row0 + 2 * q2;
    __hip_atomic_store((unsigned long long*)(hx + ho), pv,
                       __ATOMIC_RELAXED, __HIP_MEMORY_SCOPE_AGENT);
    asm volatile("s_waitcnt vmcnt(0)" ::: "memory");   // this wave's h at L3
    __syncthreads();                                   // => all waves' h at L3
    if (tid == 0)
      __hip_atomic_store(flags + (grp * GBLK + blk) * 32, (unsigned)(i + 1),
                         __ATOMIC_RELAXED, __HIP_MEMORY_SCOPE_AGENT);

    // ---- readout partials while flag propagates
#pragma unroll
    for (int cidx = 0; cidx < 2; ++cidx) {
      int cc = rg * 2 + cidx;
      int ts = cc * CHUNK - WASH; if (ts < 0) ts = 0;
      int tau = ts + i;
      int rel = tau - cc * CHUNK;
      if (rel >= 0 && rel < CHUNK) {
        int t_out = dir ? (TT - 1 - tau) : tau;
        float s = 0.f;
#pragma unroll
        for (int j = 0; j < 16; ++j)
          s += hn_sh[(l4 * 16 + j) * 17 + cc] * wout_sh[(l4 * 16 + j) * 17 + lm];
        s += __shfl_xor(s, 16);
        s += __shfl_xor(s, 32);
        if (lane < 16)
          partial[((size_t)(grp * GBLK + blk) * TT + t_out) * OO + lm] = s;
      }
    }
  }
}

__global__ __launch_bounds__(256) void combine_kernel(
    const float* __restrict__ w_out, const float* __restrict__ partial,
    float* __restrict__ out)
{
  int idx = blockIdx.x * 256 + threadIdx.x;   // (b*2048+t)*16+o
  int o = idx & 15;
  int bt = idx >> 4;
  int b_ = bt >> 11;
  int t_ = bt & 2047;
  float s = w_out[o];   // bias row
#pragma unroll 1
  for (int dir = 0; dir < 2; ++dir)
#pragma unroll
    for (int g = 0; g < 16; ++g)
      s += partial[((size_t)((dir * 8 + b_) * 16 + g) * TT + t_) * OO + o];
  out[idx] = s;
}

extern "C" void kernel_launch(void* const* d_in, const int* in_sizes, int n_in,
                              void* d_out, int out_size, void* d_ws, size_t ws_size,
                              hipStream_t stream) {
  (void)in_sizes; (void)n_in; (void)out_size; (void)ws_size;
  const float* u      = (const float*)d_in[0];
  const float* w      = (const float*)d_in[1];
  const float* w_in   = (const float*)d_in[2];
  const float* w_bias = (const float*)d_in[3];
  const float* w_out  = (const float*)d_in[4];
  float* out = (float*)d_out;
  float* ws  = (float*)d_ws;

  // zero flags + packed h double buffers each replay
  (void)hipMemsetAsync(d_ws, 0, (size_t)(WS_HX + 524288) * 4, stream);

  ucvt_kernel<<<dim3(1024), dim3(256), 0, stream>>>(
      u, (unsigned short*)(ws + WS_UHI), (unsigned short*)(ws + WS_ULO));
  esn_kernel<<<dim3(NGRP * GBLK), dim3(512), 0, stream>>>(w, w_in, w_bias, w_out, ws);
  combine_kernel<<<dim3((BB * TT * OO) / 256), dim3(256), 0, stream>>>(
      w_out, ws + WS_PART, out);
}

// Round 9
// 672.508 us; speedup vs baseline: 10.9772x; 1.3330x over previous
//
#include <hip/hip_runtime.h>

#define BB 8
#define TT 2048
#define DD 64
#define HH 1024
#define OO 16
#define NGRP 16
#define GBLK 16
#define KCH 16
#define CHUNK 128
#define WASH 64
#define STEPS (CHUNK + WASH)   // 192

typedef __attribute__((ext_vector_type(8))) short short8;
typedef __attribute__((ext_vector_type(4))) float f32x4;

// ws layout (f32 units)
// flags: [grp][producer][consumer] u32, 128B apart -> 16*16*16*32 u32
#define WS_HX   131072                  // h: [NGRP][2][KCH][HH] bf16 = 1MB
#define WS_UHI  (WS_HX + 262144)        // [BB][TT][DD] bf16
#define WS_ULO  (WS_UHI + 524288)
#define WS_PART (WS_ULO + 524288)       // [NGRP][GBLK][TT][OO] f32

__device__ __forceinline__ unsigned short f2bf(float x) {
  union { float f; unsigned u; } v; v.f = x;
  unsigned r = v.u + 0x7FFF + ((v.u >> 16) & 1);   // RNE
  return (unsigned short)(r >> 16);
}
__device__ __forceinline__ float bf2f(unsigned short h) {
  union { unsigned u; float f; } v; v.u = ((unsigned)h) << 16; return v.f;
}

// device-coherent ops (served at the coherence point; proven protocol)
__device__ __forceinline__ uint4 ld_cohx4(const void* p) {
  uint4 r;
  asm volatile("global_load_dwordx4 %0, %1, off sc0 sc1" : "=&v"(r) : "v"(p));
  return r;
}
__device__ __forceinline__ void st_coh(unsigned* p, unsigned v) {
  asm volatile("global_store_dword %0, %1, off sc0 sc1" :: "v"(p), "v"(v) : "memory");
}
__device__ __forceinline__ unsigned ld_flag(const unsigned* p) {
  unsigned r;
  asm volatile("global_load_dword %0, %1, off sc0 sc1\n\ts_waitcnt vmcnt(0)"
               : "=&v"(r) : "v"(p) : "memory");
  return r;
}

__global__ __launch_bounds__(256) void ucvt_kernel(const float* __restrict__ u,
    unsigned short* __restrict__ uhi, unsigned short* __restrict__ ulo) {
  int i = blockIdx.x * 256 + threadIdx.x;
  float4 v = ((const float4*)u)[i];
  ushort4 h, l;
  float x;
  x = v.x; h.x = f2bf(x); l.x = f2bf(x - bf2f(h.x));
  x = v.y; h.y = f2bf(x); l.y = f2bf(x - bf2f(h.y));
  x = v.z; h.z = f2bf(x); l.z = f2bf(x - bf2f(h.z));
  x = v.w; h.w = f2bf(x); l.w = f2bf(x - bf2f(h.w));
  ((ushort4*)uhi)[i] = h;
  ((ushort4*)ulo)[i] = l;
}

__global__ __launch_bounds__(512, 2) void esn_kernel(
    const float* __restrict__ w, const float* __restrict__ w_in,
    const float* __restrict__ w_bias, const float* __restrict__ w_out,
    float* __restrict__ ws)
{
  __shared__ float zp_sh[8 * 1088];   // [wave][row*17 + ch]
  __shared__ float hn_sh[64 * 17];    // [row*17 + ch]
  __shared__ float wout_sh[64 * 17];  // [row*17 + o]

  const int tid = threadIdx.x;
  const int lane = tid & 63;
  const int rg = tid >> 6;            // wave 0..7, owns k-slice [rg*128, rg*128+128)
  const int lm = lane & 15;
  const int l4 = lane >> 4;
  const int bid = blockIdx.x;
  const int grp = bid & 15;           // group = dir*8 + b
  const int blk = bid >> 4;           // owns rows [blk*64, blk*64+64)
  const int dir = grp >> 3;
  const int b = grp & 7;
  const int row0 = blk * 64;

  unsigned* flags = (unsigned*)ws;    // [(grp*16+p)*16+c]*32
  unsigned short* hx = (unsigned short*)(ws + WS_HX);
  const unsigned short* uhi = (const unsigned short*)(ws + WS_UHI);
  const unsigned short* ulo = (const unsigned short*)(ws + WS_ULO);
  float* partial = ws + WS_PART;

  // ---- A fragments (split bf16): rows row0+mt*16+lm, k=(rg*4+kt)*32+l4*8+i
  short8 Ahi[4][4], Alo[4][4];
#pragma unroll
  for (int mt = 0; mt < 4; ++mt) {
#pragma unroll
    for (int kt = 0; kt < 4; ++kt) {
      const int row = row0 + mt * 16 + lm;
      const int kb = (rg * 4 + kt) * 32 + l4 * 8;
      const float* wp = w + (size_t)row * HH + kb;
      short8 h8, l8;
#pragma unroll
      for (int i2 = 0; i2 < 2; ++i2) {
        float4 v = ((const float4*)wp)[i2];
        float xs[4] = {v.x, v.y, v.z, v.w};
#pragma unroll
        for (int j = 0; j < 4; ++j) {
          unsigned short hb = f2bf(xs[j]);
          h8[i2 * 4 + j] = (short)hb;
          l8[i2 * 4 + j] = (short)f2bf(xs[j] - bf2f(hb));
        }
      }
      Ahi[mt][kt] = h8; Alo[mt][kt] = l8;
    }
  }
  short8 UAhi[4], UAlo[4];
  if (rg < 2) {
#pragma unroll
    for (int mt = 0; mt < 4; ++mt) {
      const int row = row0 + mt * 16 + lm;
      const int kb = rg * 32 + l4 * 8;
      const float* wp = w_in + (size_t)row * DD + kb;
      short8 h8, l8;
#pragma unroll
      for (int i2 = 0; i2 < 2; ++i2) {
        float4 v = ((const float4*)wp)[i2];
        float xs[4] = {v.x, v.y, v.z, v.w};
#pragma unroll
        for (int j = 0; j < 4; ++j) {
          unsigned short hb = f2bf(xs[j]);
          h8[i2 * 4 + j] = (short)hb;
          l8[i2 * 4 + j] = (short)f2bf(xs[j] - bf2f(hb));
        }
      }
      UAhi[mt] = h8; UAlo[mt] = l8;
    }
  }

  for (int idx = tid; idx < 1024; idx += 512) {
    int r = idx >> 4, o = idx & 15;
    wout_sh[r * 17 + o] = w_out[(size_t)(1 + dir * HH + row0 + r) * OO + o];
  }

  // finalize mapping: thread -> chain ch, adjacent rows 2q2, 2q2+1
  const int ch = tid & 15;
  const int q2 = tid >> 4;            // 0..31
  const float bias0 = w_bias[row0 + 2 * q2];
  const float bias1 = w_bias[row0 + 2 * q2 + 1];
  float hp0 = 0.f, hp1 = 0.f;
  __syncthreads();

#pragma unroll 1
  for (int i = 0; i < STEPS; ++i) {
    const int par = i & 1;
    const unsigned short* hb_r = hx + ((unsigned)(grp * 2 + par) * KCH + lm) * HH;

    // ---- per-wave producer-pair poll on own replica lines (1 poller/line)
    if (i > 0) {
      const unsigned tg = (unsigned)i;
      unsigned v;
      do {
        v = 0xFFFFFFFFu;
        if (lane < 2)
          v = ld_flag(flags + ((grp * GBLK + 2 * rg + lane) * GBLK + blk) * 32);
      } while (!__all(v >= tg));
      asm volatile("" ::: "memory");
    }

    // ---- B loads: own k-slice, 4 coherent dwordx4 (hi-only bf16 h)
    uint4 Bv[4];
#pragma unroll
    for (int kt = 0; kt < 4; ++kt)
      Bv[kt] = ld_cohx4(hb_r + (rg * 4 + kt) * 32 + l4 * 8);
    uint4 uh4, ul4;
    if (rg < 2) {
      int ts = lm * CHUNK - WASH; if (ts < 0) ts = 0;
      int tau = ts + i;
      int t = dir ? (TT - 1 - tau) : tau;
      size_t ub = ((size_t)(b * TT + t)) * DD + rg * 32 + l4 * 8;
      uh4 = *(const uint4*)(uhi + ub);
      ul4 = *(const uint4*)(ulo + ub);
    }
    asm volatile("s_waitcnt vmcnt(0)" ::: "memory");
    __builtin_amdgcn_sched_barrier(0);

    f32x4 acc[4];
#pragma unroll
    for (int mt = 0; mt < 4; ++mt) acc[mt] = (f32x4){0.f, 0.f, 0.f, 0.f};

#pragma unroll
    for (int kt = 0; kt < 4; ++kt) {
      short8 bh = *(short8*)&Bv[kt];
#pragma unroll
      for (int mt = 0; mt < 4; ++mt) {
        acc[mt] = __builtin_amdgcn_mfma_f32_16x16x32_bf16(Ahi[mt][kt], bh, acc[mt], 0, 0, 0);
        acc[mt] = __builtin_amdgcn_mfma_f32_16x16x32_bf16(Alo[mt][kt], bh, acc[mt], 0, 0, 0);
      }
    }
    if (rg < 2) {
      short8 ubh = *(short8*)&uh4;
      short8 ubl = *(short8*)&ul4;
#pragma unroll
      for (int mt = 0; mt < 4; ++mt) {
        acc[mt] = __builtin_amdgcn_mfma_f32_16x16x32_bf16(UAhi[mt], ubh, acc[mt], 0, 0, 0);
        acc[mt] = __builtin_amdgcn_mfma_f32_16x16x32_bf16(UAhi[mt], ubl, acc[mt], 0, 0, 0);
        acc[mt] = __builtin_amdgcn_mfma_f32_16x16x32_bf16(UAlo[mt], ubh, acc[mt], 0, 0, 0);
      }
    }

    // ---- per-wave K-partials to LDS
#pragma unroll
    for (int mt = 0; mt < 4; ++mt)
#pragma unroll
      for (int j = 0; j < 4; ++j)
        zp_sh[rg * 1088 + (mt * 16 + l4 * 4 + j) * 17 + lm] = acc[mt][j];
    __syncthreads();

    // ---- finalize rows 2q2, 2q2+1 of chain ch
    float z0 = bias0, z1 = bias1;
#pragma unroll
    for (int g2 = 0; g2 < 8; ++g2) {
      z0 += zp_sh[g2 * 1088 + (2 * q2) * 17 + ch];
      z1 += zp_sh[g2 * 1088 + (2 * q2 + 1) * 17 + ch];
    }
    float e0 = __expf(2.0f * z0), e1 = __expf(2.0f * z1);
    float th0 = 1.0f - 2.0f * __builtin_amdgcn_rcpf(e0 + 1.0f);
    float th1 = 1.0f - 2.0f * __builtin_amdgcn_rcpf(e1 + 1.0f);
    hp0 = 0.1f * hp0 + 0.9f * th0;
    hp1 = 0.1f * hp1 + 0.9f * th1;
    hn_sh[(2 * q2) * 17 + ch] = hp0;
    hn_sh[(2 * q2 + 1) * 17 + ch] = hp1;
    // publish bf16 h (two adjacent rows in one dword)
    unsigned pv = (unsigned)f2bf(hp0) | ((unsigned)f2bf(hp1) << 16);
    const unsigned ho = ((unsigned)(grp * 2 + (par ^ 1)) * KCH + ch) * HH + row0 + 2 * q2;
    st_coh((unsigned*)(hx + ho), pv);
    asm volatile("s_waitcnt vmcnt(0)" ::: "memory");   // h at coherence point
    __syncthreads();                                   // all waves' h committed
    if (tid < 16)   // replicated flag: one line per consumer block
      st_coh(flags + ((grp * GBLK + blk) * GBLK + tid) * 32, (unsigned)(i + 1));

    // ---- readout partials while flags propagate
#pragma unroll
    for (int cidx = 0; cidx < 2; ++cidx) {
      int cc = rg * 2 + cidx;
      int ts = cc * CHUNK - WASH; if (ts < 0) ts = 0;
      int tau = ts + i;
      int rel = tau - cc * CHUNK;
      if (rel >= 0 && rel < CHUNK) {
        int t_out = dir ? (TT - 1 - tau) : tau;
        float s = 0.f;
#pragma unroll
        for (int j = 0; j < 16; ++j)
          s += hn_sh[(l4 * 16 + j) * 17 + cc] * wout_sh[(l4 * 16 + j) * 17 + lm];
        s += __shfl_xor(s, 16);
        s += __shfl_xor(s, 32);
        if (lane < 16)
          partial[((size_t)(grp * GBLK + blk) * TT + t_out) * OO + lm] = s;
      }
    }
  }
}

__global__ __launch_bounds__(256) void combine_kernel(
    const float* __restrict__ w_out, const float* __restrict__ partial,
    float* __restrict__ out)
{
  int idx = blockIdx.x * 256 + threadIdx.x;   // (b*2048+t)*16+o
  int o = idx & 15;
  int bt = idx >> 4;
  int b_ = bt >> 11;
  int t_ = bt & 2047;
  float s = w_out[o];   // bias row
#pragma unroll 1
  for (int dir = 0; dir < 2; ++dir)
#pragma unroll
    for (int g = 0; g < 16; ++g)
      s += partial[((size_t)((dir * 8 + b_) * 16 + g) * TT + t_) * OO + o];
  out[idx] = s;
}

extern "C" void kernel_launch(void* const* d_in, const int* in_sizes, int n_in,
                              void* d_out, int out_size, void* d_ws, size_t ws_size,
                              hipStream_t stream) {
  (void)in_sizes; (void)n_in; (void)out_size; (void)ws_size;
  const float* u      = (const float*)d_in[0];
  const float* w      = (const float*)d_in[1];
  const float* w_in   = (const float*)d_in[2];
  const float* w_bias = (const float*)d_in[3];
  const float* w_out  = (const float*)d_in[4];
  float* out = (float*)d_out;
  float* ws  = (float*)d_ws;

  // zero replicated flags + bf16 h double buffers each replay
  (void)hipMemsetAsync(d_ws, 0, (size_t)(WS_HX + 262144) * 4, stream);

  ucvt_kernel<<<dim3(1024), dim3(256), 0, stream>>>(
      u, (unsigned short*)(ws + WS_UHI), (unsigned short*)(ws + WS_ULO));
  esn_kernel<<<dim3(NGRP * GBLK), dim3(512), 0, stream>>>(w, w_in, w_bias, w_out, ws);
  combine_kernel<<<dim3((BB * TT * OO) / 256), dim3(256), 0, stream>>>(
      w_out, ws + WS_PART, out);
}

// Round 11
// 611.525 us; speedup vs baseline: 12.0719x; 1.0997x over previous
//
#include <hip/hip_runtime.h>

#define BB 8
#define TT 2048
#define DD 64
#define HH 1024
#define OO 16
#define NGRP 16
#define GBLK 16
#define KCH 16
#define CHUNK 128
#define WASH 48
#define STEPS (CHUNK + WASH)   // 176
#define ZPS 36                 // zp stride: 2-way banks on write AND finalize read

typedef __attribute__((ext_vector_type(8))) short short8;
typedef __attribute__((ext_vector_type(4))) float f32x4;

// ws layout (f32 units)
// flags: [grp][producer][consumer] u32, 128B apart -> 16*16*16*32 u32
#define WS_HX   131072                  // h: [NGRP][2][KCH][HH] bf16 = 1MB
#define WS_UHI  (WS_HX + 262144)        // [BB][TT][DD] bf16
#define WS_ULO  (WS_UHI + 524288)
#define WS_PART (WS_ULO + 524288)       // [NGRP][GBLK][TT][OO] f32

__device__ __forceinline__ unsigned short f2bf(float x) {
  union { float f; unsigned u; } v; v.f = x;
  unsigned r = v.u + 0x7FFF + ((v.u >> 16) & 1);   // RNE
  return (unsigned short)(r >> 16);
}
__device__ __forceinline__ float bf2f(unsigned short h) {
  union { unsigned u; float f; } v; v.u = ((unsigned)h) << 16; return v.f;
}

// device-coherent ops (served at the coherence point; proven protocol)
__device__ __forceinline__ uint4 ld_cohx4(const void* p) {
  uint4 r;
  asm volatile("global_load_dwordx4 %0, %1, off sc0 sc1" : "=&v"(r) : "v"(p));
  return r;
}
__device__ __forceinline__ void st_coh(unsigned* p, unsigned v) {
  asm volatile("global_store_dword %0, %1, off sc0 sc1" :: "v"(p), "v"(v) : "memory");
}
__device__ __forceinline__ unsigned ld_flag(const unsigned* p) {
  unsigned r;
  asm volatile("global_load_dword %0, %1, off sc0 sc1\n\ts_waitcnt vmcnt(0)"
               : "=&v"(r) : "v"(p) : "memory");
  return r;
}

__global__ __launch_bounds__(256) void ucvt_kernel(const float* __restrict__ u,
    unsigned short* __restrict__ uhi, unsigned short* __restrict__ ulo) {
  int i = blockIdx.x * 256 + threadIdx.x;
  float4 v = ((const float4*)u)[i];
  ushort4 h, l;
  float x;
  x = v.x; h.x = f2bf(x); l.x = f2bf(x - bf2f(h.x));
  x = v.y; h.y = f2bf(x); l.y = f2bf(x - bf2f(h.y));
  x = v.z; h.z = f2bf(x); l.z = f2bf(x - bf2f(h.z));
  x = v.w; h.w = f2bf(x); l.w = f2bf(x - bf2f(h.w));
  ((ushort4*)uhi)[i] = h;
  ((ushort4*)ulo)[i] = l;
}

__global__ __launch_bounds__(512) void esn_kernel(
    const float* __restrict__ w, const float* __restrict__ w_in,
    const float* __restrict__ w_bias, const float* __restrict__ w_out,
    float* __restrict__ ws)
{
  __shared__ float zp_sh[8 * 64 * ZPS];  // [wave][row*ZPS + ch]
  __shared__ float hn_sh[64 * 17];       // [row*17 + ch]
  __shared__ float wout_sh[64 * 17];     // [row*17 + o]

  const int tid = threadIdx.x;
  const int lane = tid & 63;
  const int rg = tid >> 6;            // wave 0..7, owns k-slice [rg*128, rg*128+128)
  const int lm = lane & 15;
  const int l4 = lane >> 4;
  const int bid = blockIdx.x;
  const int grp = bid & 15;           // group = dir*8 + b
  const int blk = bid >> 4;           // owns rows [blk*64, blk*64+64)
  const int dir = grp >> 3;
  const int b = grp & 7;
  const int row0 = blk * 64;

  unsigned* flags = (unsigned*)ws;    // [(grp*16+p)*16+c]*32
  unsigned short* hx = (unsigned short*)(ws + WS_HX);
  const unsigned short* uhi = (const unsigned short*)(ws + WS_UHI);
  const unsigned short* ulo = (const unsigned short*)(ws + WS_ULO);
  float* partial = ws + WS_PART;

  // ---- A fragments (split bf16): rows row0+mt*16+lm, k=(rg*4+kt)*32+l4*8+i
  short8 Ahi[4][4], Alo[4][4];
#pragma unroll
  for (int mt = 0; mt < 4; ++mt) {
#pragma unroll
    for (int kt = 0; kt < 4; ++kt) {
      const int row = row0 + mt * 16 + lm;
      const int kb = (rg * 4 + kt) * 32 + l4 * 8;
      const float* wp = w + (size_t)row * HH + kb;
      short8 h8, l8;
#pragma unroll
      for (int i2 = 0; i2 < 2; ++i2) {
        float4 v = ((const float4*)wp)[i2];
        float xs[4] = {v.x, v.y, v.z, v.w};
#pragma unroll
        for (int j = 0; j < 4; ++j) {
          unsigned short hb = f2bf(xs[j]);
          h8[i2 * 4 + j] = (short)hb;
          l8[i2 * 4 + j] = (short)f2bf(xs[j] - bf2f(hb));
        }
      }
      Ahi[mt][kt] = h8; Alo[mt][kt] = l8;
    }
  }
  short8 UAhi[4], UAlo[4];
  if (rg < 2) {
#pragma unroll
    for (int mt = 0; mt < 4; ++mt) {
      const int row = row0 + mt * 16 + lm;
      const int kb = rg * 32 + l4 * 8;
      const float* wp = w_in + (size_t)row * DD + kb;
      short8 h8, l8;
#pragma unroll
      for (int i2 = 0; i2 < 2; ++i2) {
        float4 v = ((const float4*)wp)[i2];
        float xs[4] = {v.x, v.y, v.z, v.w};
#pragma unroll
        for (int j = 0; j < 4; ++j) {
          unsigned short hb = f2bf(xs[j]);
          h8[i2 * 4 + j] = (short)hb;
          l8[i2 * 4 + j] = (short)f2bf(xs[j] - bf2f(hb));
        }
      }
      UAhi[mt] = h8; UAlo[mt] = l8;
    }
  }

  for (int idx = tid; idx < 1024; idx += 512) {
    int r = idx >> 4, o = idx & 15;
    wout_sh[r * 17 + o] = w_out[(size_t)(1 + dir * HH + row0 + r) * OO + o];
  }

  // finalize mapping: thread -> chain ch, adjacent rows 2q2, 2q2+1
  const int ch = tid & 15;
  const int q2 = tid >> 4;            // 0..31
  const float bias0 = w_bias[row0 + 2 * q2];
  const float bias1 = w_bias[row0 + 2 * q2 + 1];
  float hp0 = 0.f, hp1 = 0.f;
  __syncthreads();

#pragma unroll 1
  for (int i = 0; i < STEPS; ++i) {
    const int par = i & 1;
    const unsigned short* hb_r = hx + ((unsigned)(grp * 2 + par) * KCH + lm) * HH;

    // ---- u fragment first (independent of h; latency overlaps the poll)
    uint4 uh4, ul4;
    if (rg < 2) {
      int ts = lm * CHUNK - WASH; if (ts < 0) ts = 0;
      int tau = ts + i;
      int t = dir ? (TT - 1 - tau) : tau;
      size_t ub = ((size_t)(b * TT + t)) * DD + rg * 32 + l4 * 8;
      uh4 = *(const uint4*)(uhi + ub);
      ul4 = *(const uint4*)(ulo + ub);
    }

    // ---- per-wave producer-pair poll on own replica lines (1 poller/line)
    if (i > 0) {
      const unsigned tg = (unsigned)i;
      unsigned v;
      do {
        v = 0xFFFFFFFFu;
        if (lane < 2)
          v = ld_flag(flags + ((grp * GBLK + 2 * rg + lane) * GBLK + blk) * 32);
      } while (!__all(v >= tg));
      asm volatile("" ::: "memory");
    }

    // ---- B loads: own k-slice, 4 coherent dwordx4 (hi-only bf16 h)
    uint4 Bv[4];
#pragma unroll
    for (int kt = 0; kt < 4; ++kt)
      Bv[kt] = ld_cohx4(hb_r + (rg * 4 + kt) * 32 + l4 * 8);
    asm volatile("s_waitcnt vmcnt(0)" ::: "memory");
    __builtin_amdgcn_sched_barrier(0);

    f32x4 acc[4];
#pragma unroll
    for (int mt = 0; mt < 4; ++mt) acc[mt] = (f32x4){0.f, 0.f, 0.f, 0.f};

#pragma unroll
    for (int kt = 0; kt < 4; ++kt) {
      short8 bh = *(short8*)&Bv[kt];
#pragma unroll
      for (int mt = 0; mt < 4; ++mt) {
        acc[mt] = __builtin_amdgcn_mfma_f32_16x16x32_bf16(Ahi[mt][kt], bh, acc[mt], 0, 0, 0);
        acc[mt] = __builtin_amdgcn_mfma_f32_16x16x32_bf16(Alo[mt][kt], bh, acc[mt], 0, 0, 0);
      }
    }
    if (rg < 2) {
      short8 ubh = *(short8*)&uh4;
      short8 ubl = *(short8*)&ul4;
#pragma unroll
      for (int mt = 0; mt < 4; ++mt) {
        acc[mt] = __builtin_amdgcn_mfma_f32_16x16x32_bf16(UAhi[mt], ubh, acc[mt], 0, 0, 0);
        acc[mt] = __builtin_amdgcn_mfma_f32_16x16x32_bf16(UAhi[mt], ubl, acc[mt], 0, 0, 0);
        acc[mt] = __builtin_amdgcn_mfma_f32_16x16x32_bf16(UAlo[mt], ubh, acc[mt], 0, 0, 0);
      }
    }

    // ---- per-wave K-partials to LDS (stride ZPS=36: conflict-free 2-way)
#pragma unroll
    for (int mt = 0; mt < 4; ++mt)
#pragma unroll
      for (int j = 0; j < 4; ++j)
        zp_sh[rg * (64 * ZPS) + (mt * 16 + l4 * 4 + j) * ZPS + lm] = acc[mt][j];
    __syncthreads();

    // ---- finalize rows 2q2, 2q2+1 of chain ch
    float z0 = bias0, z1 = bias1;
#pragma unroll
    for (int g2 = 0; g2 < 8; ++g2) {
      z0 += zp_sh[g2 * (64 * ZPS) + (2 * q2) * ZPS + ch];
      z1 += zp_sh[g2 * (64 * ZPS) + (2 * q2 + 1) * ZPS + ch];
    }
    float e0 = __expf(2.0f * z0), e1 = __expf(2.0f * z1);
    float th0 = 1.0f - 2.0f * __builtin_amdgcn_rcpf(e0 + 1.0f);
    float th1 = 1.0f - 2.0f * __builtin_amdgcn_rcpf(e1 + 1.0f);
    hp0 = 0.1f * hp0 + 0.9f * th0;
    hp1 = 0.1f * hp1 + 0.9f * th1;
    hn_sh[(2 * q2) * 17 + ch] = hp0;
    hn_sh[(2 * q2 + 1) * 17 + ch] = hp1;
    // publish bf16 h (two adjacent rows in one dword)
    unsigned pv = (unsigned)f2bf(hp0) | ((unsigned)f2bf(hp1) << 16);
    const unsigned ho = ((unsigned)(grp * 2 + (par ^ 1)) * KCH + ch) * HH + row0 + 2 * q2;
    st_coh((unsigned*)(hx + ho), pv);
    asm volatile("s_waitcnt vmcnt(0)" ::: "memory");   // h at coherence point
    __syncthreads();                                   // all waves' h committed
    if (tid < 16)   // replicated flag: one line per consumer block
      st_coh(flags + ((grp * GBLK + blk) * GBLK + tid) * 32, (unsigned)(i + 1));

    // ---- readout partials while flags propagate
#pragma unroll
    for (int cidx = 0; cidx < 2; ++cidx) {
      int cc = rg * 2 + cidx;
      int ts = cc * CHUNK - WASH; if (ts < 0) ts = 0;
      int tau = ts + i;
      int rel = tau - cc * CHUNK;
      if (rel >= 0 && rel < CHUNK) {
        int t_out = dir ? (TT - 1 - tau) : tau;
        float s = 0.f;
#pragma unroll
        for (int j = 0; j < 16; ++j)
          s += hn_sh[(l4 * 16 + j) * 17 + cc] * wout_sh[(l4 * 16 + j) * 17 + lm];
        s += __shfl_xor(s, 16);
        s += __shfl_xor(s, 32);
        if (lane < 16)
          partial[((size_t)(grp * GBLK + blk) * TT + t_out) * OO + lm] = s;
      }
    }
  }
}

__global__ __launch_bounds__(256) void combine_kernel(
    const float* __restrict__ w_out, const float* __restrict__ partial,
    float* __restrict__ out)
{
  int idx = blockIdx.x * 256 + threadIdx.x;   // (b*2048+t)*16+o
  int o = idx & 15;
  int bt = idx >> 4;
  int b_ = bt >> 11;
  int t_ = bt & 2047;
  float s = w_out[o];   // bias row
#pragma unroll 1
  for (int dir = 0; dir < 2; ++dir)
#pragma unroll
    for (int g = 0; g < 16; ++g)
      s += partial[((size_t)((dir * 8 + b_) * 16 + g) * TT + t_) * OO + o];
  out[idx] = s;
}

extern "C" void kernel_launch(void* const* d_in, const int* in_sizes, int n_in,
                              void* d_out, int out_size, void* d_ws, size_t ws_size,
                              hipStream_t stream) {
  (void)in_sizes; (void)n_in; (void)out_size; (void)ws_size;
  const float* u      = (const float*)d_in[0];
  const float* w      = (const float*)d_in[1];
  const float* w_in   = (const float*)d_in[2];
  const float* w_bias = (const float*)d_in[3];
  const float* w_out  = (const float*)d_in[4];
  float* out = (float*)d_out;
  float* ws  = (float*)d_ws;

  // zero replicated flags + bf16 h double buffers each replay
  (void)hipMemsetAsync(d_ws, 0, (size_t)(WS_HX + 262144) * 4, stream);

  ucvt_kernel<<<dim3(1024), dim3(256), 0, stream>>>(
      u, (unsigned short*)(ws + WS_UHI), (unsigned short*)(ws + WS_ULO));
  esn_kernel<<<dim3(NGRP * GBLK), dim3(512), 0, stream>>>(w, w_in, w_bias, w_out, ws);
  combine_kernel<<<dim3((BB * TT * OO) / 256), dim3(256), 0, stream>>>(
      w_out, ws + WS_PART, out);
}